// Round 1
// baseline (340.844 us; speedup 1.0000x reference)
//
#include <hip/hip_runtime.h>

// Problem constants (from setup_inputs): N=5, B=16, H=W=384, J=17
#define NF 5
#define NB 16
#define NH 384
#define NW 384
#define NJ 17
#define HW (NH * NW)

// charbonnier(x) = (x^2 + (1e-9)^2)^0.25
__device__ __forceinline__ float charb(float x) {
    return sqrtf(sqrtf(fmaf(x, x, 1e-18f)));
}

// ws layout (floats): [0]=sup_sum, [1]=denom(count), [2]=unsup_acc (pre /B)

__global__ __launch_bounds__(512)
void kp_kernel(const float* __restrict__ kps, const float* __restrict__ pf,
               float* __restrict__ ws) {
    __shared__ int cnt;
    __shared__ int ebase[NB * NJ];
    __shared__ float edx[NB * NJ], edy[NB * NJ];
    if (threadIdx.x == 0) cnt = 0;
    __syncthreads();

    int t = threadIdx.x;
    if (t < NB * NJ) {
        int b = t / NJ, j = t % NJ;
        const float* k0 = kps + ((size_t)(b * 2 + 0) * NJ + j) * 2;
        const float* k1 = kps + ((size_t)(b * 2 + 1) * NJ + j) * 2;
        float x0 = k0[0], y0 = k0[1], x1 = k1[0], y1 = k1[1];
        bool valid = (x0 >= 0.f) && (y0 >= 0.f) && (x1 >= 0.f) && (y1 >= 0.f) &&
                     (x0 < (float)NW) && (y0 < (float)NH) &&
                     (x1 < (float)NW) && (y1 < (float)NH);
        float dx = x1 - x0, dy = y1 - y0;
        if (valid && (dx != 0.f || dy != 0.f)) {
            int xi = (int)floorf(x0);
            int yi = (int)floorf(y0);
            int s = atomicAdd(&cnt, 1);
            ebase[s] = (b * 2) * HW + yi * NW + xi;   // offset of channel-0 elem for flow i=0
            edx[s] = dx; edy[s] = dy;
        }
    }
    __syncthreads();

    const float wts[NF] = {0.4096f, 0.512f, 0.64f, 0.8f, 1.0f};
    int n = cnt;
    float local = 0.f;
    for (int q = threadIdx.x; q < n * NF; q += blockDim.x) {
        int e = q / NF, i = q - e * NF;
        int off = ebase[e] + i * (NB * 2 * HW);
        float p0 = pf[off];
        float p1 = pf[off + HW];
        float ex = p0 - edx[e], ey = p1 - edy[e];
        local += wts[i] * sqrtf(ex * ex + ey * ey);
    }
    // block reduce (512 threads = 8 waves)
    for (int o = 32; o > 0; o >>= 1) local += __shfl_down(local, o, 64);
    __shared__ float ssum[8];
    int lane = threadIdx.x & 63, wid = threadIdx.x >> 6;
    if (lane == 0) ssum[wid] = local;
    __syncthreads();
    if (threadIdx.x == 0) {
        float s = 0.f;
        #pragma unroll
        for (int k = 0; k < 8; ++k) s += ssum[k];
        ws[0] = s;
        ws[1] = (float)n;
    }
}

__global__ __launch_bounds__(256)
void unsup_kernel(const float* __restrict__ pf, const float* __restrict__ frm0,
                  const float* __restrict__ frm1, float* __restrict__ acc) {
    const float wts[NF] = {0.4096f, 0.512f, 0.64f, 0.8f, 1.0f};
    const float SC = (float)(NW - 1) / (float)NW;  // (W-1)/W == (H-1)/H here

    float local = 0.f;
    const int total = NF * NB * HW;
    for (int idx = blockIdx.x * blockDim.x + threadIdx.x; idx < total;
         idx += gridDim.x * blockDim.x) {
        int w = idx % NW;
        int t = idx / NW;
        int h = t % NH;
        int t2 = t / NH;
        int b = t2 % NB;
        int i = t2 / NB;

        int fbase = (i * NB + b) * 2 * HW;
        int off = h * NW + w;
        float fx = pf[fbase + off];
        float fy = pf[fbase + HW + off];

        // smoothness: down + right neighbors, zero-padded at edges
        float dnx = 0.f, dny = 0.f, rtx = 0.f, rty = 0.f;
        if (h < NH - 1) { dnx = pf[fbase + off + NW]; dny = pf[fbase + HW + off + NW]; }
        if (w < NW - 1) { rtx = pf[fbase + off + 1];  rty = pf[fbase + HW + off + 1]; }
        float smooth = 0.5f * (charb(fx - dnx) + charb(fy - dny) +
                               charb(fx - rtx) + charb(fy - rty));

        // photometric: bilinear zero-pad sample of frm1 at (xp, yp)
        float xp = (fx + (float)w) * SC;
        float yp = (fy + (float)h) * SC;
        float x0f = floorf(xp), y0f = floorf(yp);
        float wx1 = xp - x0f, wx0 = 1.f - wx1;
        float wy1 = yp - y0f, wy0 = 1.f - wy1;
        bool vx0 = (x0f >= 0.f) && (x0f <= (float)(NW - 1));
        bool vx1 = (x0f + 1.f >= 0.f) && (x0f + 1.f <= (float)(NW - 1));
        bool vy0 = (y0f >= 0.f) && (y0f <= (float)(NH - 1));
        bool vy1 = (y0f + 1.f >= 0.f) && (y0f + 1.f <= (float)(NH - 1));
        float m00 = (vx0 && vy0) ? wx0 * wy0 : 0.f;
        float m10 = (vx1 && vy0) ? wx1 * wy0 : 0.f;
        float m01 = (vx0 && vy1) ? wx0 * wy1 : 0.f;
        float m11 = (vx1 && vy1) ? wx1 * wy1 : 0.f;
        int x0i = min(max((int)x0f, 0), NW - 1);
        int x1i = min(x0i + 1, NW - 1);
        int y0i = min(max((int)y0f, 0), NH - 1);
        int y1i = min(y0i + 1, NH - 1);
        int r0 = y0i * NW, r1 = y1i * NW;

        int ibase = b * 3 * HW;
        float phot = 0.f;
        #pragma unroll
        for (int c = 0; c < 3; ++c) {
            const float* img = frm1 + ibase + c * HW;
            float s = m00 * img[r0 + x0i] + m10 * img[r0 + x1i] +
                      m01 * img[r1 + x0i] + m11 * img[r1 + x1i];
            float d = s - frm0[ibase + c * HW + off];
            phot += charb(d);
        }
        local += wts[i] * (phot * (1.f / 3.f) + smooth);
    }

    // block reduce (256 threads = 4 waves)
    for (int o = 32; o > 0; o >>= 1) local += __shfl_down(local, o, 64);
    __shared__ float ssum[4];
    int lane = threadIdx.x & 63, wid = threadIdx.x >> 6;
    if (lane == 0) ssum[wid] = local;
    __syncthreads();
    if (threadIdx.x == 0) {
        atomicAdd(acc, ssum[0] + ssum[1] + ssum[2] + ssum[3]);
    }
}

__global__ void final_kernel(const float* __restrict__ ws, float* __restrict__ out) {
    if (threadIdx.x == 0) {
        float denom = fmaxf(ws[1], 1.0f);
        out[0] = ws[2] * (1.0f / (float)NB) + ws[0] / denom;
    }
}

extern "C" void kernel_launch(void* const* d_in, const int* in_sizes, int n_in,
                              void* d_out, int out_size, void* d_ws, size_t ws_size,
                              hipStream_t stream) {
    const float* pf   = (const float*)d_in[0];  // (5,16,2,384,384)
    const float* kps  = (const float*)d_in[1];  // (16,2,17,2)
    const float* frm0 = (const float*)d_in[2];  // (16,3,384,384)
    const float* frm1 = (const float*)d_in[3];  // (16,3,384,384)
    float* out = (float*)d_out;
    float* ws  = (float*)d_ws;

    hipMemsetAsync(ws, 0, 3 * sizeof(float), stream);
    kp_kernel<<<1, 512, 0, stream>>>(kps, pf, ws);
    unsup_kernel<<<4096, 256, 0, stream>>>(pf, frm0, frm1, ws + 2);
    final_kernel<<<1, 64, 0, stream>>>(ws, out);
}